// Round 3
// baseline (362.470 us; speedup 1.0000x reference)
//
#include <hip/hip_runtime.h>

// B=8, T=1024, D=1024, H=16, DH=64.
// Column softmax (axis=-2): attn[q,k] = exp(S[q,k])/sum_q' exp(S[q',k]).
// Input dtype (fp32 vs bf16) detected on-device; pipeline runs bf16+fp32 accum.

typedef __bf16 bf16_t;
typedef __bf16 bf16x8 __attribute__((ext_vector_type(8)));
typedef float f32x4 __attribute__((ext_vector_type(4)));
typedef unsigned short u16x8 __attribute__((ext_vector_type(8)));

#define DEV __device__ __forceinline__
#define SCALE 0.125f  // DH^-0.5

DEV void gld_lds16(const bf16_t* g, bf16_t* l) {
  __builtin_amdgcn_global_load_lds(
      (const __attribute__((address_space(1))) unsigned int*)g,
      (__attribute__((address_space(3))) unsigned int*)l, 16, 0, 0);
}

// Sanitizers: inert for sane data, make inf/NaN structurally impossible.
DEV float expc(float x) { return __expf(fminf(fmaxf(x, -60.f), 60.f)); }
DEV float sanit(float v) {
  return (v == v) ? fminf(fmaxf(v, -1e4f), 1e4f) : 0.f;
}

// Swizzled chunk (8 bf16 = 16B) offsets in elements. Swizzle baked into the
// staging GLOBAL address so the LDS side stays linear (global_load_lds req).
DEV int sw64(int r, int kc) { return r * 64 + (((kc ^ (r + (r >> 3))) & 7) << 3); }
DEV int sw32(int r, int kc) { return r * 32 + (((kc ^ r ^ (r >> 2)) & 3) << 3); }

DEV f32x4 mfma16(bf16x8 a, bf16x8 b, f32x4 c) {
  return __builtin_amdgcn_mfma_f32_16x16x32_bf16(a, b, c, 0, 0, 0);
}

// ---------------- dtype probe: bf16 data has exp<=~130; fp32 misread has ----
// ---------------- random exponents -> max over 16K samples >= 160 -----------
__global__ void detect_dtype(const unsigned short* x, int* flag) {
  __shared__ int smax;
  if (threadIdx.x == 0) smax = 0;
  __syncthreads();
  int m = 0;
  for (int i = threadIdx.x; i < 16384; i += 256) {
    int e = (x[i] >> 7) & 0xFF;
    m = m > e ? m : e;
  }
  atomicMax(&smax, m);
  __syncthreads();
  if (threadIdx.x == 0) *flag = (smax >= 160) ? 1 : 0;
}

// ---------------- canonicalize input to bf16 (cast if fp32, copy if bf16) ---
__global__ void convert_in(const void* __restrict__ src, bf16_t* __restrict__ dst,
                           int n8, const int* __restrict__ flag) {
  int i = blockIdx.x * 256 + threadIdx.x;
  if (i >= n8) return;
  if (*flag) {
    const float4* s = (const float4*)src;
    float4 a = s[i * 2], b = s[i * 2 + 1];
    bf16x8 o;
    o[0] = (bf16_t)a.x; o[1] = (bf16_t)a.y; o[2] = (bf16_t)a.z; o[3] = (bf16_t)a.w;
    o[4] = (bf16_t)b.x; o[5] = (bf16_t)b.y; o[6] = (bf16_t)b.z; o[7] = (bf16_t)b.w;
    *(bf16x8*)(dst + (size_t)i * 8) = o;
  } else {
    ((u16x8*)dst)[i] = ((const u16x8*)src)[i];
  }
}

// --------- C[m][n] = sum_k A[m][k]*B[n][k], 128x128 tile, BK=32 -------------
// A row stride lda; C row stride ldc; output bf16 (Cb) or fp32 (Cf) per flag.
__global__ __launch_bounds__(256, 2)
void gemm_bt(const bf16_t* __restrict__ A, int lda, const bf16_t* __restrict__ B,
             bf16_t* __restrict__ Cb, float* __restrict__ Cf, int ldc,
             int K, const int* __restrict__ f32flag) {
  __shared__ bf16_t sA[128 * 32];
  __shared__ bf16_t sB[128 * 32];
  const int tid = threadIdx.x;
  const int wave = tid >> 6, lane = tid & 63;
  const int l = lane & 15, quad = lane >> 4;
  const int row0 = blockIdx.y * 128, col0 = blockIdx.x * 128;
  const int wm = (wave >> 1) * 64, wn = (wave & 1) * 64;
  f32x4 acc[4][4];
#pragma unroll
  for (int i = 0; i < 4; ++i)
#pragma unroll
    for (int j = 0; j < 4; ++j) acc[i][j] = f32x4{0.f, 0.f, 0.f, 0.f};

  for (int k0 = 0; k0 < K; k0 += 32) {
    __syncthreads();
#pragma unroll
    for (int t = 0; t < 2; ++t) {
      int base = t * 256 + wave * 64;
      int n = base + lane;
      int r = n >> 2;
      int kc = ((n & 3) ^ r ^ (r >> 2)) & 3;
      gld_lds16(A + (size_t)(row0 + r) * lda + k0 + kc * 8, sA + base * 8);
      gld_lds16(B + (size_t)(col0 + r) * K + k0 + kc * 8, sB + base * 8);
    }
    __syncthreads();
    bf16x8 af[4], bfr[4];
#pragma unroll
    for (int i = 0; i < 4; ++i)
      af[i] = *(const bf16x8*)&sA[sw32(wm + i * 16 + l, quad)];
#pragma unroll
    for (int j = 0; j < 4; ++j)
      bfr[j] = *(const bf16x8*)&sB[sw32(wn + j * 16 + l, quad)];
#pragma unroll
    for (int i = 0; i < 4; ++i)
#pragma unroll
      for (int j = 0; j < 4; ++j)
        acc[i][j] = mfma16(af[i], bfr[j], acc[i][j]);
  }
  const bool of32 = (f32flag != nullptr) && (*f32flag != 0);
#pragma unroll
  for (int i = 0; i < 4; ++i) {
    int rr = row0 + wm + i * 16 + quad * 4;
#pragma unroll
    for (int j = 0; j < 4; ++j) {
      int cc = col0 + wn + j * 16 + l;
#pragma unroll
      for (int t = 0; t < 4; ++t) {
        float v = sanit(acc[i][j][t]);
        size_t idx = (size_t)(rr + t) * ldc + cc;
        if (of32) Cf[idx] = v; else Cb[idx] = (bf16_t)v;
      }
    }
  }
}

// ------------- K2: column sumexp L[k] (and V transpose) per (bh, ktile) ------
__global__ __launch_bounds__(256, 2)
void attn_stats(const bf16_t* __restrict__ qkv, bf16_t* __restrict__ Vt,
                float* __restrict__ rcpL) {
  __shared__ bf16_t sK[128 * 64];
  __shared__ bf16_t sQ[128 * 64];
  __shared__ float sL[128];
  const int kt = blockIdx.x, bh = blockIdx.y;
  const int b = bh >> 4, h = bh & 15;
  const int tid = threadIdx.x, wave = tid >> 6, lane = tid & 63;
  const int l = lane & 15, quad = lane >> 4;
  const size_t rowK = (size_t)b * 1024 + kt * 128;

  // stage V-tile (into sQ) and K-tile (into sK), swizzled
#pragma unroll
  for (int t = 0; t < 4; ++t) {
    int base = wave * 256 + t * 64;
    int n = base + lane;
    int r = n >> 3;
    int kc = ((n & 7) ^ (r + (r >> 3))) & 7;
    gld_lds16(qkv + (rowK + r) * 3072 + 2048 + h * 64 + kc * 8, sQ + base * 8);
    gld_lds16(qkv + (rowK + r) * 3072 + 1024 + h * 64 + kc * 8, sK + base * 8);
  }
  if (tid < 128) sL[tid] = 0.f;
  __syncthreads();

  // write V transposed: Vt[bh*64+d][t]
#pragma unroll
  for (int t = 0; t < 4; ++t) {
    int u = t * 256 + tid;
    int d = u >> 4, k0 = (u & 15) * 8;
    u16x8 pk;
#pragma unroll
    for (int i = 0; i < 8; ++i) {
      int k = k0 + i;
      pk[i] = *(const unsigned short*)&sQ[sw64(k, d >> 3) + (d & 7)];
    }
    *(u16x8*)&Vt[((size_t)bh * 64 + d) * 1024 + kt * 128 + k0] = pk;
  }
  __syncthreads();

  for (int qt = 0; qt < 8; ++qt) {
#pragma unroll
    for (int t = 0; t < 4; ++t) {
      int base = wave * 256 + t * 64;
      int n = base + lane;
      int r = n >> 3;
      int kc = ((n & 7) ^ (r + (r >> 3))) & 7;
      gld_lds16(qkv + ((size_t)b * 1024 + qt * 128 + r) * 3072 + h * 64 + kc * 8,
                sQ + base * 8);
    }
    __syncthreads();
    bf16x8 aq[2][2];
#pragma unroll
    for (int i = 0; i < 2; ++i)
#pragma unroll
      for (int ks = 0; ks < 2; ++ks)
        aq[i][ks] = *(const bf16x8*)&sQ[sw64(wave * 32 + i * 16 + l, ks * 4 + quad)];
#pragma unroll
    for (int j = 0; j < 8; ++j) {
      f32x4 s0 = {0.f, 0.f, 0.f, 0.f}, s1 = {0.f, 0.f, 0.f, 0.f};
#pragma unroll
      for (int ks = 0; ks < 2; ++ks) {
        bf16x8 bk = *(const bf16x8*)&sK[sw64(j * 16 + l, ks * 4 + quad)];
        s0 = mfma16(aq[0][ks], bk, s0);
        s1 = mfma16(aq[1][ks], bk, s1);
      }
      float sum = 0.f;
#pragma unroll
      for (int t = 0; t < 4; ++t)
        sum += expc(s0[t] * SCALE) + expc(s1[t] * SCALE);
      sum += __shfl_xor(sum, 16);
      sum += __shfl_xor(sum, 32);
      if (lane < 16) atomicAdd(&sL[j * 16 + l], sum);
    }
    __syncthreads();
  }
  if (tid < 128)
    rcpL[(size_t)bh * 1024 + kt * 128 + tid] = 1.0f / fmaxf(sL[tid], 1e-20f);
}

// ------------- K3: O[q][d] = sum_k exp(S[q,k])*rcpL[k]*V[k][d] ---------------
// attn output written into qkv's V-columns (stride 3072, offset 2048) --
// those are dead after K2's Vt transpose and never read by K3.
__global__ __launch_bounds__(256, 2)
void attn_out_k(const bf16_t* __restrict__ qkv, const bf16_t* __restrict__ Vt,
                const float* __restrict__ rcpL, bf16_t* __restrict__ attn) {
  __shared__ bf16_t sQ[128 * 64];
  __shared__ bf16_t sKP[128 * 136];  // union: K-tile (first 8192 el) / P (stride 136)
  __shared__ float sLb[128];
  const int qt = blockIdx.x, bh = blockIdx.y;
  const int b = bh >> 4, h = bh & 15;
  const int tid = threadIdx.x, wave = tid >> 6, lane = tid & 63;
  const int l = lane & 15, quad = lane >> 4;

  // stage Q once
#pragma unroll
  for (int t = 0; t < 4; ++t) {
    int base = wave * 256 + t * 64;
    int n = base + lane;
    int r = n >> 3;
    int kc = ((n & 7) ^ (r + (r >> 3))) & 7;
    gld_lds16(qkv + ((size_t)b * 1024 + qt * 128 + r) * 3072 + h * 64 + kc * 8,
              sQ + base * 8);
  }
  f32x4 o[2][4];
#pragma unroll
  for (int i = 0; i < 2; ++i)
#pragma unroll
    for (int jd = 0; jd < 4; ++jd) o[i][jd] = f32x4{0.f, 0.f, 0.f, 0.f};

  for (int kt = 0; kt < 8; ++kt) {
    __syncthreads();  // prev iter's sKP reads done (also Q-stage drain at kt=0)
#pragma unroll
    for (int t = 0; t < 4; ++t) {
      int base = wave * 256 + t * 64;
      int n = base + lane;
      int r = n >> 3;
      int kc = ((n & 7) ^ (r + (r >> 3))) & 7;
      gld_lds16(qkv + ((size_t)b * 1024 + kt * 128 + r) * 3072 + 1024 + h * 64 + kc * 8,
                sKP + base * 8);
    }
    if (tid < 128) sLb[tid] = rcpL[(size_t)bh * 1024 + kt * 128 + tid];
    __syncthreads();  // staging visible

    // S = Q K^T
    f32x4 s[2][8];
    bf16x8 aq[2][2];
#pragma unroll
    for (int i = 0; i < 2; ++i)
#pragma unroll
      for (int ks = 0; ks < 2; ++ks)
        aq[i][ks] = *(const bf16x8*)&sQ[sw64(wave * 32 + i * 16 + l, ks * 4 + quad)];
#pragma unroll
    for (int j = 0; j < 8; ++j) {
      s[0][j] = f32x4{0.f, 0.f, 0.f, 0.f};
      s[1][j] = f32x4{0.f, 0.f, 0.f, 0.f};
#pragma unroll
      for (int ks = 0; ks < 2; ++ks) {
        bf16x8 bk = *(const bf16x8*)&sKP[sw64(j * 16 + l, ks * 4 + quad)];
        s[0][j] = mfma16(aq[0][ks], bk, s[0][j]);
        s[1][j] = mfma16(aq[1][ks], bk, s[1][j]);
      }
    }
    __syncthreads();  // all waves done reading K region before P overwrite

    // P = exp(S*scale)*rcpL, C-layout -> LDS (A-layout readable, stride 136)
#pragma unroll
    for (int j = 0; j < 8; ++j) {
      float rl = sLb[j * 16 + l];
#pragma unroll
      for (int i = 0; i < 2; ++i) {
        int row = wave * 32 + i * 16 + quad * 4;
#pragma unroll
        for (int t = 0; t < 4; ++t) {
          float p = fminf(expc(s[i][j][t] * SCALE) * rl, 1e4f);
          sKP[(row + t) * 136 + j * 16 + l] = (bf16_t)p;
        }
      }
    }
    __syncthreads();  // P visible

    // O += P @ V ; V fragment direct from global Vt (reused 32x, L2-served)
#pragma unroll
    for (int ks = 0; ks < 4; ++ks) {
      bf16x8 ap[2];
#pragma unroll
      for (int i = 0; i < 2; ++i)
        ap[i] = *(const bf16x8*)&sKP[(wave * 32 + i * 16 + l) * 136 + (ks * 4 + quad) * 8];
#pragma unroll
      for (int jd = 0; jd < 4; ++jd) {
        bf16x8 bv = *(const bf16x8*)&Vt[((size_t)bh * 64 + jd * 16 + l) * 1024 +
                                        kt * 128 + (ks * 4 + quad) * 8];
        o[0][jd] = mfma16(ap[0], bv, o[0][jd]);
        o[1][jd] = mfma16(ap[1], bv, o[1][jd]);
      }
    }
  }
  // epilogue: attn[(b*1024 + q)*3072 + h*64 + d]  (V-columns of qkv, stride 3072)
#pragma unroll
  for (int i = 0; i < 2; ++i) {
    int row = qt * 128 + wave * 32 + i * 16 + quad * 4;
#pragma unroll
    for (int jd = 0; jd < 4; ++jd) {
      int dd = h * 64 + jd * 16 + l;
#pragma unroll
      for (int t = 0; t < 4; ++t)
        attn[((size_t)b * 1024 + row + t) * 3072 + dd] = (bf16_t)sanit(o[i][jd][t]);
    }
  }
}

extern "C" void kernel_launch(void* const* d_in, const int* in_sizes, int n_in,
                              void* d_out, int out_size, void* d_ws, size_t ws_size,
                              hipStream_t stream) {
  (void)in_sizes; (void)n_in; (void)out_size; (void)ws_size;
  char* w = (char*)d_ws;
  // ws plan (75.6 MB):
  bf16_t* qkv = (bf16_t*)w;                        // [0, 50331648)
  bf16_t* xb = (bf16_t*)(w + 50331648);            // [50331648, 67108864)  -> Vt after K1
  bf16_t* Vt = xb;                                 //   (xb dead once K1 done)
  bf16_t* Wqkvb = (bf16_t*)(w + 67108864);         // [67108864, 73400320)  -> rcpL after K1
  float* rcpL = (float*)(w + 67108864);
  bf16_t* Wprojb = (bf16_t*)(w + 73400320);        // [73400320, 75497472)
  int* flag = (int*)(w + 75497472);
  bf16_t* attn = qkv + 2048;                       // V-columns of qkv, stride 3072

  detect_dtype<<<1, 256, 0, stream>>>((const unsigned short*)d_in[0], flag);
  convert_in<<<4096, 256, 0, stream>>>(d_in[0], xb, 1048576, flag);
  convert_in<<<1536, 256, 0, stream>>>(d_in[1], Wqkvb, 393216, flag);
  convert_in<<<512, 256, 0, stream>>>(d_in[2], Wprojb, 131072, flag);

  // K1: qkv = x @ Wqkv^T   (8192 x 3072, K=1024), bf16 out
  gemm_bt<<<dim3(24, 64), 256, 0, stream>>>(xb, 1024, Wqkvb, qkv, nullptr, 3072,
                                            1024, nullptr);
  // K2: column softmax denominators + V transpose
  attn_stats<<<dim3(8, 128), 256, 0, stream>>>(qkv, Vt, rcpL);
  // K3: attention output -> qkv V-columns
  attn_out_k<<<dim3(8, 128), 256, 0, stream>>>(qkv, Vt, rcpL, attn);
  // K4: out = attn @ Wproj^T  (8192 x 1024, K=1024), dtype per flag
  gemm_bt<<<dim3(8, 64), 256, 0, stream>>>(attn, 3072, Wprojb, (bf16_t*)d_out,
                                           (float*)d_out, 1024, 1024, flag);
}